// Round 4
// baseline (693.385 us; speedup 1.0000x reference)
//
#include <hip/hip_runtime.h>
#include <hip/hip_fp16.h>

#define BN_EPS 1e-5f

__device__ __forceinline__ float4 f4zero() { return make_float4(0.f, 0.f, 0.f, 0.f); }

// ---------------- graph preprocessing ----------------

__global__ __launch_bounds__(256) void k_hist(const int* __restrict__ dst,
                                              int* __restrict__ counts, int e) {
    int i = blockIdx.x * 256 + threadIdx.x;
    if (i < e) atomicAdd(&counts[dst[i]], 1);
}

__global__ __launch_bounds__(256) void k_dinv(const int* __restrict__ counts,
                                              float* __restrict__ dinv, int n) {
    int i = blockIdx.x * 256 + threadIdx.x;
    if (i < n) dinv[i] = rsqrtf((float)(counts[i] + 1));  // +1 = self loop, always > 0
}

// exclusive scan of PADDED counts ((c+7)&~7) so every node's edge list is a
// multiple of 8 records and 32 B aligned.
__global__ __launch_bounds__(1024) void k_scan_block(const int* __restrict__ counts,
                                                     int* __restrict__ offs,
                                                     int* __restrict__ partials, int n) {
    __shared__ int s[1024];
    int t = threadIdx.x;
    int gid = blockIdx.x * 1024 + t;
    int c = (gid < n) ? counts[gid] : 0;
    int v = (c + 7) & ~7;
    int x = v;
    s[t] = x;
    __syncthreads();
    for (int d = 1; d < 1024; d <<= 1) {
        int y = (t >= d) ? s[t - d] : 0;
        __syncthreads();
        x += y;
        s[t] = x;
        __syncthreads();
    }
    if (gid < n) offs[gid] = x - v;               // exclusive scan within block
    if (t == 1023) partials[blockIdx.x] = x;      // block total
}

// parallel scan of block partials (nb <= 1024). partials[i] -> exclusive, partials[nb] = total
__global__ __launch_bounds__(1024) void k_scan_partials(int* __restrict__ partials, int nb) {
    __shared__ int s[1024];
    int t = threadIdx.x;
    int v = (t < nb) ? partials[t] : 0;
    int x = v;
    s[t] = x;
    __syncthreads();
    for (int d = 1; d < 1024; d <<= 1) {
        int y = (t >= d) ? s[t - d] : 0;
        __syncthreads();
        x += y;
        s[t] = x;
        __syncthreads();
    }
    if (t < nb) partials[t] = x - v;
    if (t == nb - 1) partials[nb] = x;
}

__global__ __launch_bounds__(256) void k_scan_add(int* __restrict__ offs,
                                                  const int* __restrict__ partials, int n) {
    int gid = blockIdx.x * 256 + threadIdx.x;
    if (gid < n) offs[gid] += partials[gid >> 10];
    if (gid == 0) offs[n] = partials[(n + 1023) >> 10];
}

// prefill er with the dummy (zero-row) index so padding slots gather zeros
__global__ __launch_bounds__(256) void k_fill(int4* __restrict__ er4, int val, int m4) {
    int i = blockIdx.x * 256 + threadIdx.x;
    if (i < m4) er4[i] = make_int4(val, val, val, val);
}

// scatter src index into CSR slot; cursor pre-initialized to offs (d2d copy)
__global__ __launch_bounds__(256) void k_place(const int* __restrict__ src,
                                               const int* __restrict__ dst,
                                               int* __restrict__ cursor,
                                               int* __restrict__ er, int e) {
    int i = blockIdx.x * 256 + threadIdx.x;
    if (i < e) {
        int d = dst[i], s = src[i];
        int p = atomicAdd(&cursor[d], 1);
        __builtin_nontemporal_store(s, er + p);
    }
}

// ---------------- GEMM: C[n,128](f16) = (A[n,128](f32) @ W[128,128](f32)) * dinv[row] ----
// dinv[row] folded into the stored row => all edge weights in aggregation become 1.

__global__ __launch_bounds__(256) void k_gemm128(const float* __restrict__ A,
                                                 const float* __restrict__ W,
                                                 const float* __restrict__ dinv,
                                                 uint2* __restrict__ C, int n) {
    __shared__ float Ws[64 * 128];   // 32 KB: one 64-row chunk of W
    __shared__ float As[64 * 128];   // 32 KB: A tile, full K=128
    int tid = threadIdx.x;
    int row0 = blockIdx.x * 64;

    {   // stage A tile (2048 float4, 8 per thread)
        const float4* Av = (const float4*)A;
        float4* Asv = (float4*)As;
#pragma unroll
        for (int i = 0; i < 8; ++i) {
            int idx = tid + 256 * i;          // 0..2047
            int r = idx >> 5;                 // row in tile
            int row = row0 + r;
            Asv[idx] = (row < n) ? Av[row * 32 + (idx & 31)] : f4zero();
        }
    }

    int cg = tid & 31;     // cols 4*cg .. 4*cg+3
    int rid = tid >> 5;    // rows rid*8 .. rid*8+7
    float4 acc[8];
#pragma unroll
    for (int r = 0; r < 8; ++r) acc[r] = f4zero();

    const float4* Asv = (const float4*)As;
    const float4* Wsv = (const float4*)Ws;
    const float4* Wv = (const float4*)W;

    for (int kh = 0; kh < 2; ++kh) {
        __syncthreads();
        {   // stage W rows [kh*64, kh*64+64): 2048 float4
            float4* Wsw = (float4*)Ws;
#pragma unroll
            for (int i = 0; i < 8; ++i) {
                int idx = tid + 256 * i;
                Wsw[idx] = Wv[kh * 2048 + idx];
            }
        }
        __syncthreads();
#pragma unroll 4
        for (int k4 = 0; k4 < 16; ++k4) {   // local k-quad within chunk
            float4 w0 = Wsv[(4 * k4 + 0) * 32 + cg];
            float4 w1 = Wsv[(4 * k4 + 1) * 32 + cg];
            float4 w2 = Wsv[(4 * k4 + 2) * 32 + cg];
            float4 w3 = Wsv[(4 * k4 + 3) * 32 + cg];
#pragma unroll
            for (int r = 0; r < 8; ++r) {
                float4 a = Asv[(rid * 8 + r) * 32 + (kh * 16 + k4)];
                acc[r].x += a.x * w0.x; acc[r].x += a.y * w1.x; acc[r].x += a.z * w2.x; acc[r].x += a.w * w3.x;
                acc[r].y += a.x * w0.y; acc[r].y += a.y * w1.y; acc[r].y += a.z * w2.y; acc[r].y += a.w * w3.y;
                acc[r].z += a.x * w0.z; acc[r].z += a.y * w1.z; acc[r].z += a.z * w2.z; acc[r].z += a.w * w3.z;
                acc[r].w += a.x * w0.w; acc[r].w += a.y * w1.w; acc[r].w += a.z * w2.w; acc[r].w += a.w * w3.w;
            }
        }
    }

#pragma unroll
    for (int r = 0; r < 8; ++r) {
        int row = row0 + rid * 8 + r;
        if (row < n) {
            float di = dinv[row];
            __half2 p0 = __floats2half2_rn(acc[r].x * di, acc[r].y * di);
            __half2 p1 = __floats2half2_rn(acc[r].z * di, acc[r].w * di);
            uint2 u;
            u.x = *(unsigned int*)&p0;
            u.y = *(unsigned int*)&p1;
            C[row * 32 + cg] = u;   // row = 32 x uint2 = 128 halfs = 256 B
        }
    }
}

// ---------------- CSR aggregation + bias + ReLU + BN (+ optional classifier) ----------------
// 32 lanes per node; gathers pre-scaled f16 rows, unweighted f32 accumulate,
// final scale by dinv[node]. Edge lists padded to x8 with zero-row index.

__device__ __forceinline__ void acc_row(float4& acc, uint2 q) {
    float2 f01 = __half22float2(*(__half2*)&q.x);
    float2 f23 = __half22float2(*(__half2*)&q.y);
    acc.x += f01.x; acc.y += f01.y; acc.z += f23.x; acc.w += f23.y;
}

template <bool FUSE_CLS>
__global__ __launch_bounds__(256) void k_aggregate(const uint2* __restrict__ Ah,
                                                   const int* __restrict__ offs,
                                                   const int* __restrict__ er,
                                                   const float* __restrict__ dinv,
                                                   const float* __restrict__ bias,
                                                   const float* __restrict__ g,
                                                   const float* __restrict__ be,
                                                   const float* __restrict__ rm,
                                                   const float* __restrict__ rv,
                                                   float4* __restrict__ Hout,
                                                   const float* __restrict__ Wc,
                                                   const float* __restrict__ bc,
                                                   float* __restrict__ out, int n) {
    int lane = threadIdx.x & 31;
    int node = blockIdx.x * 8 + (threadIdx.x >> 5);
    if (node >= n) return;

    float4 acc = f4zero();
    acc_row(acc, Ah[node * 32 + lane]);           // self loop (weight folds to dinv^2)

    int e0 = offs[node], e1 = offs[node + 1];
    for (int e = e0; e < e1; e += 8) {            // always full, aligned batches of 8
        int4 ra = *(const int4*)(er + e);
        int4 rb = *(const int4*)(er + e + 4);
        uint2 v0 = Ah[ra.x * 32 + lane];
        uint2 v1 = Ah[ra.y * 32 + lane];
        uint2 v2 = Ah[ra.z * 32 + lane];
        uint2 v3 = Ah[ra.w * 32 + lane];
        uint2 v4 = Ah[rb.x * 32 + lane];
        uint2 v5 = Ah[rb.y * 32 + lane];
        uint2 v6 = Ah[rb.z * 32 + lane];
        uint2 v7 = Ah[rb.w * 32 + lane];
        acc_row(acc, v0); acc_row(acc, v1); acc_row(acc, v2); acc_row(acc, v3);
        acc_row(acc, v4); acc_row(acc, v5); acc_row(acc, v6); acc_row(acc, v7);
    }

    float di = dinv[node];
    acc.x *= di; acc.y *= di; acc.z *= di; acc.w *= di;

    float4 b4  = ((const float4*)bias)[lane];
    float4 g4  = ((const float4*)g)[lane];
    float4 be4 = ((const float4*)be)[lane];
    float4 rm4 = ((const float4*)rm)[lane];
    float4 rv4 = ((const float4*)rv)[lane];

    float4 o;
    float v;
    v = fmaxf(acc.x + b4.x, 0.f); o.x = (v - rm4.x) * rsqrtf(rv4.x + BN_EPS) * g4.x + be4.x;
    v = fmaxf(acc.y + b4.y, 0.f); o.y = (v - rm4.y) * rsqrtf(rv4.y + BN_EPS) * g4.y + be4.y;
    v = fmaxf(acc.z + b4.z, 0.f); o.z = (v - rm4.z) * rsqrtf(rv4.z + BN_EPS) * g4.z + be4.z;
    v = fmaxf(acc.w + b4.w, 0.f); o.w = (v - rm4.w) * rsqrtf(rv4.w + BN_EPS) * g4.w + be4.w;

    if (!FUSE_CLS) {
        Hout[node * 32 + lane] = o;
    } else {
        const float4* Wv = (const float4*)Wc;       // Wc row-major [128][2]
        float4 w01 = Wv[2 * lane];                  // (Wc[k][0],Wc[k][1],Wc[k+1][0],Wc[k+1][1])
        float4 w23 = Wv[2 * lane + 1];
        float p0 = o.x * w01.x + o.y * w01.z + o.z * w23.x + o.w * w23.z;
        float p1 = o.x * w01.y + o.y * w01.w + o.z * w23.y + o.w * w23.w;
#pragma unroll
        for (int d = 16; d >= 1; d >>= 1) {
            p0 += __shfl_down(p0, d, 32);
            p1 += __shfl_down(p1, d, 32);
        }
        if (lane == 0) {
            out[node * 2 + 0] = p0 + bc[0];
            out[node * 2 + 1] = p1 + bc[1];
        }
    }
}

// ---------------- launch ----------------

extern "C" void kernel_launch(void* const* d_in, const int* in_sizes, int n_in,
                              void* d_out, int out_size, void* d_ws, size_t ws_size,
                              hipStream_t stream) {
    const float* x   = (const float*)d_in[0];
    const int*   ei  = (const int*)d_in[1];    // [2,E] int32 (JAX demotes int64)
    const float* W1  = (const float*)d_in[2];
    const float* b1  = (const float*)d_in[3];
    const float* W2  = (const float*)d_in[4];
    const float* b2  = (const float*)d_in[5];
    const float* W3  = (const float*)d_in[6];
    const float* b3  = (const float*)d_in[7];
    const float* g1  = (const float*)d_in[8];
    const float* be1 = (const float*)d_in[9];
    const float* rm1 = (const float*)d_in[10];
    const float* rv1 = (const float*)d_in[11];
    const float* g2  = (const float*)d_in[12];
    const float* be2 = (const float*)d_in[13];
    const float* rm2 = (const float*)d_in[14];
    const float* rv2 = (const float*)d_in[15];
    const float* g3  = (const float*)d_in[16];
    const float* be3 = (const float*)d_in[17];
    const float* rm3 = (const float*)d_in[18];
    const float* rv3 = (const float*)d_in[19];
    const float* Wc  = (const float*)d_in[20];
    const float* bc  = (const float*)d_in[21];
    float* out = (float*)d_out;

    int n = in_sizes[0] / 128;
    int e = in_sizes[1] / 2;
    const int* src = ei;
    const int* dst = ei + e;

    char* ws = (char*)d_ws;
    size_t off = 0;
    auto alloc = [&](size_t bytes) -> char* {
        char* p = ws + off;
        off += (bytes + 255) & ~(size_t)255;
        return p;
    };
    int erCap = e + 8 * n;                                   // padded CSR capacity
    uint2* bufA   = (uint2*)alloc((size_t)(n + 1) * 128 * 2); // GEMM out f16, +1 zero row
    float* bufH   = (float*)alloc((size_t)n * 128 * 4);       // aggregated hidden, f32
    float* dinv   = (float*)alloc((size_t)n * 4);
    int*   counts = (int*)  alloc((size_t)n * 4);
    int*   offs   = (int*)  alloc((size_t)(n + 1) * 4);
    int*   cursor = (int*)  alloc((size_t)n * 4);
    int*   parts  = (int*)  alloc(8192);
    int*   er     = (int*)  alloc((size_t)erCap * 4);
    (void)ws_size; (void)n_in; (void)out_size;

    hipMemsetAsync(counts, 0, (size_t)n * 4, stream);
    hipMemsetAsync(bufA + (size_t)n * 32, 0, 256, stream);   // zero row n (padding target)

    int gE = (e + 255) / 256;
    int gN = (n + 255) / 256;
    int nb = (n + 1023) / 1024;
    int m4 = erCap / 4;

    k_hist<<<gE, 256, 0, stream>>>(dst, counts, e);
    k_dinv<<<gN, 256, 0, stream>>>(counts, dinv, n);
    k_scan_block<<<nb, 1024, 0, stream>>>(counts, offs, parts, n);
    k_scan_partials<<<1, 1024, 0, stream>>>(parts, nb);
    k_scan_add<<<gN, 256, 0, stream>>>(offs, parts, n);
    hipMemcpyAsync(cursor, offs, (size_t)n * 4, hipMemcpyDeviceToDevice, stream);
    k_fill<<<(m4 + 255) / 256, 256, 0, stream>>>((int4*)er, n, m4);
    k_place<<<gE, 256, 0, stream>>>(src, dst, cursor, er, e);

    int gGemm = (n + 63) / 64;
    int gAgg  = (n + 7) / 8;

    k_gemm128<<<gGemm, 256, 0, stream>>>(x, W1, dinv, bufA, n);
    k_aggregate<false><<<gAgg, 256, 0, stream>>>(bufA, offs, er, dinv,
                                                 b1, g1, be1, rm1, rv1, (float4*)bufH,
                                                 nullptr, nullptr, nullptr, n);

    k_gemm128<<<gGemm, 256, 0, stream>>>(bufH, W2, dinv, bufA, n);
    k_aggregate<false><<<gAgg, 256, 0, stream>>>(bufA, offs, er, dinv,
                                                 b2, g2, be2, rm2, rv2, (float4*)bufH,
                                                 nullptr, nullptr, nullptr, n);

    k_gemm128<<<gGemm, 256, 0, stream>>>(bufH, W3, dinv, bufA, n);
    k_aggregate<true><<<gAgg, 256, 0, stream>>>(bufA, offs, er, dinv,
                                                b3, g3, be3, rm3, rv3, nullptr,
                                                Wc, bc, out, n);
}

// Round 5
// 691.670 us; speedup vs baseline: 1.0025x; 1.0025x over previous
//
#include <hip/hip_runtime.h>
#include <hip/hip_fp16.h>

#define BN_EPS 1e-5f

__device__ __forceinline__ float4 f4zero() { return make_float4(0.f, 0.f, 0.f, 0.f); }

// ---------------- graph preprocessing ----------------

__global__ __launch_bounds__(256) void k_hist(const int* __restrict__ dst,
                                              int* __restrict__ counts, int e) {
    int i = blockIdx.x * 256 + threadIdx.x;
    if (i < e) atomicAdd(&counts[dst[i]], 1);
}

__global__ __launch_bounds__(256) void k_dinv(const int* __restrict__ counts,
                                              float* __restrict__ dinv, int n) {
    int i = blockIdx.x * 256 + threadIdx.x;
    if (i < n) dinv[i] = rsqrtf((float)(counts[i] + 1));  // +1 = self loop, always > 0
}

// exclusive scan of PADDED counts ((c+7)&~7) so every node's edge list is a
// multiple of 8 records and 32 B aligned.
__global__ __launch_bounds__(1024) void k_scan_block(const int* __restrict__ counts,
                                                     int* __restrict__ offs,
                                                     int* __restrict__ partials, int n) {
    __shared__ int s[1024];
    int t = threadIdx.x;
    int gid = blockIdx.x * 1024 + t;
    int c = (gid < n) ? counts[gid] : 0;
    int v = (c + 7) & ~7;
    int x = v;
    s[t] = x;
    __syncthreads();
    for (int d = 1; d < 1024; d <<= 1) {
        int y = (t >= d) ? s[t - d] : 0;
        __syncthreads();
        x += y;
        s[t] = x;
        __syncthreads();
    }
    if (gid < n) offs[gid] = x - v;               // exclusive scan within block
    if (t == 1023) partials[blockIdx.x] = x;      // block total
}

// parallel scan of block partials (nb <= 1024). partials[i] -> exclusive, partials[nb] = total
__global__ __launch_bounds__(1024) void k_scan_partials(int* __restrict__ partials, int nb) {
    __shared__ int s[1024];
    int t = threadIdx.x;
    int v = (t < nb) ? partials[t] : 0;
    int x = v;
    s[t] = x;
    __syncthreads();
    for (int d = 1; d < 1024; d <<= 1) {
        int y = (t >= d) ? s[t - d] : 0;
        __syncthreads();
        x += y;
        s[t] = x;
        __syncthreads();
    }
    if (t < nb) partials[t] = x - v;
    if (t == nb - 1) partials[nb] = x;
}

__global__ __launch_bounds__(256) void k_scan_add(int* __restrict__ offs,
                                                  const int* __restrict__ partials, int n) {
    int gid = blockIdx.x * 256 + threadIdx.x;
    if (gid < n) offs[gid] += partials[gid >> 10];
    if (gid == 0) offs[n] = partials[(n + 1023) >> 10];
}

// prefill er with the dummy (zero-row) index so padding slots gather zeros
__global__ __launch_bounds__(256) void k_fill(int4* __restrict__ er4, int val, int m4) {
    int i = blockIdx.x * 256 + threadIdx.x;
    if (i < m4) er4[i] = make_int4(val, val, val, val);
}

// scatter src index into CSR slot; cursor pre-initialized to offs (d2d copy).
// 4 edges per thread: int4-coalesced reads, 4 independent atomics in flight
// (MLP on the random-line atomic latency). Regular stores — NT store was a
// measured 60% regression here (R4): it defeats L2 write-combining of
// adjacent same-dst CSR slots.
__global__ __launch_bounds__(256) void k_place(const int* __restrict__ src,
                                               const int* __restrict__ dst,
                                               int* __restrict__ cursor,
                                               int* __restrict__ er, int e) {
    int base = (blockIdx.x * 256 + threadIdx.x) * 4;
    if (base + 3 < e) {
        int4 s4 = *(const int4*)(src + base);
        int4 d4 = *(const int4*)(dst + base);
        int p0 = atomicAdd(&cursor[d4.x], 1);
        int p1 = atomicAdd(&cursor[d4.y], 1);
        int p2 = atomicAdd(&cursor[d4.z], 1);
        int p3 = atomicAdd(&cursor[d4.w], 1);
        er[p0] = s4.x;
        er[p1] = s4.y;
        er[p2] = s4.z;
        er[p3] = s4.w;
    } else {
        for (int i = base; i < e; ++i) {
            int d = dst[i], s = src[i];
            int p = atomicAdd(&cursor[d], 1);
            er[p] = s;
        }
    }
}

// ---------------- GEMM: C[n,128](f16) = (A[n,128](f32) @ W[128,128](f32)) * dinv[row] ----
// dinv[row] folded into the stored row => all edge weights in aggregation become 1.

__global__ __launch_bounds__(256) void k_gemm128(const float* __restrict__ A,
                                                 const float* __restrict__ W,
                                                 const float* __restrict__ dinv,
                                                 uint2* __restrict__ C, int n) {
    __shared__ float Ws[64 * 128];   // 32 KB: one 64-row chunk of W
    __shared__ float As[64 * 128];   // 32 KB: A tile, full K=128
    int tid = threadIdx.x;
    int row0 = blockIdx.x * 64;

    {   // stage A tile (2048 float4, 8 per thread)
        const float4* Av = (const float4*)A;
        float4* Asv = (float4*)As;
#pragma unroll
        for (int i = 0; i < 8; ++i) {
            int idx = tid + 256 * i;          // 0..2047
            int r = idx >> 5;                 // row in tile
            int row = row0 + r;
            Asv[idx] = (row < n) ? Av[row * 32 + (idx & 31)] : f4zero();
        }
    }

    int cg = tid & 31;     // cols 4*cg .. 4*cg+3
    int rid = tid >> 5;    // rows rid*8 .. rid*8+7
    float4 acc[8];
#pragma unroll
    for (int r = 0; r < 8; ++r) acc[r] = f4zero();

    const float4* Asv = (const float4*)As;
    const float4* Wsv = (const float4*)Ws;
    const float4* Wv = (const float4*)W;

    for (int kh = 0; kh < 2; ++kh) {
        __syncthreads();
        {   // stage W rows [kh*64, kh*64+64): 2048 float4
            float4* Wsw = (float4*)Ws;
#pragma unroll
            for (int i = 0; i < 8; ++i) {
                int idx = tid + 256 * i;
                Wsw[idx] = Wv[kh * 2048 + idx];
            }
        }
        __syncthreads();
#pragma unroll 4
        for (int k4 = 0; k4 < 16; ++k4) {   // local k-quad within chunk
            float4 w0 = Wsv[(4 * k4 + 0) * 32 + cg];
            float4 w1 = Wsv[(4 * k4 + 1) * 32 + cg];
            float4 w2 = Wsv[(4 * k4 + 2) * 32 + cg];
            float4 w3 = Wsv[(4 * k4 + 3) * 32 + cg];
#pragma unroll
            for (int r = 0; r < 8; ++r) {
                float4 a = Asv[(rid * 8 + r) * 32 + (kh * 16 + k4)];
                acc[r].x += a.x * w0.x; acc[r].x += a.y * w1.x; acc[r].x += a.z * w2.x; acc[r].x += a.w * w3.x;
                acc[r].y += a.x * w0.y; acc[r].y += a.y * w1.y; acc[r].y += a.z * w2.y; acc[r].y += a.w * w3.y;
                acc[r].z += a.x * w0.z; acc[r].z += a.y * w1.z; acc[r].z += a.z * w2.z; acc[r].z += a.w * w3.z;
                acc[r].w += a.x * w0.w; acc[r].w += a.y * w1.w; acc[r].w += a.z * w2.w; acc[r].w += a.w * w3.w;
            }
        }
    }

#pragma unroll
    for (int r = 0; r < 8; ++r) {
        int row = row0 + rid * 8 + r;
        if (row < n) {
            float di = dinv[row];
            __half2 p0 = __floats2half2_rn(acc[r].x * di, acc[r].y * di);
            __half2 p1 = __floats2half2_rn(acc[r].z * di, acc[r].w * di);
            uint2 u;
            u.x = *(unsigned int*)&p0;
            u.y = *(unsigned int*)&p1;
            C[row * 32 + cg] = u;   // row = 32 x uint2 = 128 halfs = 256 B
        }
    }
}

// ---------------- CSR aggregation + bias + ReLU + BN (+ optional classifier) ----------------
// 32 lanes per node; gathers pre-scaled f16 rows, unweighted f32 accumulate,
// final scale by dinv[node]. Edge lists padded to x8 with zero-row index.

__device__ __forceinline__ void acc_row(float4& acc, uint2 q) {
    float2 f01 = __half22float2(*(__half2*)&q.x);
    float2 f23 = __half22float2(*(__half2*)&q.y);
    acc.x += f01.x; acc.y += f01.y; acc.z += f23.x; acc.w += f23.y;
}

template <bool FUSE_CLS>
__global__ __launch_bounds__(256) void k_aggregate(const uint2* __restrict__ Ah,
                                                   const int* __restrict__ offs,
                                                   const int* __restrict__ er,
                                                   const float* __restrict__ dinv,
                                                   const float* __restrict__ bias,
                                                   const float* __restrict__ g,
                                                   const float* __restrict__ be,
                                                   const float* __restrict__ rm,
                                                   const float* __restrict__ rv,
                                                   float4* __restrict__ Hout,
                                                   const float* __restrict__ Wc,
                                                   const float* __restrict__ bc,
                                                   float* __restrict__ out, int n) {
    int lane = threadIdx.x & 31;
    int node = blockIdx.x * 8 + (threadIdx.x >> 5);
    if (node >= n) return;

    float4 acc = f4zero();
    acc_row(acc, Ah[node * 32 + lane]);           // self loop (weight folds to dinv^2)

    int e0 = offs[node], e1 = offs[node + 1];
    for (int e = e0; e < e1; e += 8) {            // always full, aligned batches of 8
        int4 ra = *(const int4*)(er + e);
        int4 rb = *(const int4*)(er + e + 4);
        uint2 v0 = Ah[ra.x * 32 + lane];
        uint2 v1 = Ah[ra.y * 32 + lane];
        uint2 v2 = Ah[ra.z * 32 + lane];
        uint2 v3 = Ah[ra.w * 32 + lane];
        uint2 v4 = Ah[rb.x * 32 + lane];
        uint2 v5 = Ah[rb.y * 32 + lane];
        uint2 v6 = Ah[rb.z * 32 + lane];
        uint2 v7 = Ah[rb.w * 32 + lane];
        acc_row(acc, v0); acc_row(acc, v1); acc_row(acc, v2); acc_row(acc, v3);
        acc_row(acc, v4); acc_row(acc, v5); acc_row(acc, v6); acc_row(acc, v7);
    }

    float di = dinv[node];
    acc.x *= di; acc.y *= di; acc.z *= di; acc.w *= di;

    float4 b4  = ((const float4*)bias)[lane];
    float4 g4  = ((const float4*)g)[lane];
    float4 be4 = ((const float4*)be)[lane];
    float4 rm4 = ((const float4*)rm)[lane];
    float4 rv4 = ((const float4*)rv)[lane];

    float4 o;
    float v;
    v = fmaxf(acc.x + b4.x, 0.f); o.x = (v - rm4.x) * rsqrtf(rv4.x + BN_EPS) * g4.x + be4.x;
    v = fmaxf(acc.y + b4.y, 0.f); o.y = (v - rm4.y) * rsqrtf(rv4.y + BN_EPS) * g4.y + be4.y;
    v = fmaxf(acc.z + b4.z, 0.f); o.z = (v - rm4.z) * rsqrtf(rv4.z + BN_EPS) * g4.z + be4.z;
    v = fmaxf(acc.w + b4.w, 0.f); o.w = (v - rm4.w) * rsqrtf(rv4.w + BN_EPS) * g4.w + be4.w;

    if (!FUSE_CLS) {
        Hout[node * 32 + lane] = o;
    } else {
        const float4* Wv = (const float4*)Wc;       // Wc row-major [128][2]
        float4 w01 = Wv[2 * lane];                  // (Wc[k][0],Wc[k][1],Wc[k+1][0],Wc[k+1][1])
        float4 w23 = Wv[2 * lane + 1];
        float p0 = o.x * w01.x + o.y * w01.z + o.z * w23.x + o.w * w23.z;
        float p1 = o.x * w01.y + o.y * w01.w + o.z * w23.y + o.w * w23.w;
#pragma unroll
        for (int d = 16; d >= 1; d >>= 1) {
            p0 += __shfl_down(p0, d, 32);
            p1 += __shfl_down(p1, d, 32);
        }
        if (lane == 0) {
            out[node * 2 + 0] = p0 + bc[0];
            out[node * 2 + 1] = p1 + bc[1];
        }
    }
}

// ---------------- launch ----------------

extern "C" void kernel_launch(void* const* d_in, const int* in_sizes, int n_in,
                              void* d_out, int out_size, void* d_ws, size_t ws_size,
                              hipStream_t stream) {
    const float* x   = (const float*)d_in[0];
    const int*   ei  = (const int*)d_in[1];    // [2,E] int32 (JAX demotes int64)
    const float* W1  = (const float*)d_in[2];
    const float* b1  = (const float*)d_in[3];
    const float* W2  = (const float*)d_in[4];
    const float* b2  = (const float*)d_in[5];
    const float* W3  = (const float*)d_in[6];
    const float* b3  = (const float*)d_in[7];
    const float* g1  = (const float*)d_in[8];
    const float* be1 = (const float*)d_in[9];
    const float* rm1 = (const float*)d_in[10];
    const float* rv1 = (const float*)d_in[11];
    const float* g2  = (const float*)d_in[12];
    const float* be2 = (const float*)d_in[13];
    const float* rm2 = (const float*)d_in[14];
    const float* rv2 = (const float*)d_in[15];
    const float* g3  = (const float*)d_in[16];
    const float* be3 = (const float*)d_in[17];
    const float* rm3 = (const float*)d_in[18];
    const float* rv3 = (const float*)d_in[19];
    const float* Wc  = (const float*)d_in[20];
    const float* bc  = (const float*)d_in[21];
    float* out = (float*)d_out;

    int n = in_sizes[0] / 128;
    int e = in_sizes[1] / 2;
    const int* src = ei;
    const int* dst = ei + e;

    char* ws = (char*)d_ws;
    size_t off = 0;
    auto alloc = [&](size_t bytes) -> char* {
        char* p = ws + off;
        off += (bytes + 255) & ~(size_t)255;
        return p;
    };
    int erCap = e + 8 * n;                                   // padded CSR capacity
    uint2* bufA   = (uint2*)alloc((size_t)(n + 1) * 128 * 2); // GEMM out f16, +1 zero row
    float* bufH   = (float*)alloc((size_t)n * 128 * 4);       // aggregated hidden, f32
    float* dinv   = (float*)alloc((size_t)n * 4);
    int*   counts = (int*)  alloc((size_t)n * 4);
    int*   offs   = (int*)  alloc((size_t)(n + 1) * 4);
    int*   cursor = (int*)  alloc((size_t)n * 4);
    int*   parts  = (int*)  alloc(8192);
    int*   er     = (int*)  alloc((size_t)erCap * 4);
    (void)ws_size; (void)n_in; (void)out_size;

    hipMemsetAsync(counts, 0, (size_t)n * 4, stream);
    hipMemsetAsync(bufA + (size_t)n * 32, 0, 256, stream);   // zero row n (padding target)

    int gE = (e + 255) / 256;
    int gN = (n + 255) / 256;
    int nb = (n + 1023) / 1024;
    int m4 = erCap / 4;

    k_hist<<<gE, 256, 0, stream>>>(dst, counts, e);
    k_dinv<<<gN, 256, 0, stream>>>(counts, dinv, n);
    k_scan_block<<<nb, 1024, 0, stream>>>(counts, offs, parts, n);
    k_scan_partials<<<1, 1024, 0, stream>>>(parts, nb);
    k_scan_add<<<gN, 256, 0, stream>>>(offs, parts, n);
    hipMemcpyAsync(cursor, offs, (size_t)n * 4, hipMemcpyDeviceToDevice, stream);
    k_fill<<<(m4 + 255) / 256, 256, 0, stream>>>((int4*)er, n, m4);
    int gP = (e / 4 + 255) / 256 + 1;    // 4 edges per thread
    k_place<<<gP, 256, 0, stream>>>(src, dst, cursor, er, e);

    int gGemm = (n + 63) / 64;
    int gAgg  = (n + 7) / 8;

    k_gemm128<<<gGemm, 256, 0, stream>>>(x, W1, dinv, bufA, n);
    k_aggregate<false><<<gAgg, 256, 0, stream>>>(bufA, offs, er, dinv,
                                                 b1, g1, be1, rm1, rv1, (float4*)bufH,
                                                 nullptr, nullptr, nullptr, n);

    k_gemm128<<<gGemm, 256, 0, stream>>>(bufH, W2, dinv, bufA, n);
    k_aggregate<false><<<gAgg, 256, 0, stream>>>(bufA, offs, er, dinv,
                                                 b2, g2, be2, rm2, rv2, (float4*)bufH,
                                                 nullptr, nullptr, nullptr, n);

    k_gemm128<<<gGemm, 256, 0, stream>>>(bufH, W3, dinv, bufA, n);
    k_aggregate<true><<<gAgg, 256, 0, stream>>>(bufA, offs, er, dinv,
                                                b3, g3, be3, rm3, rv3, nullptr,
                                                Wc, bc, out, n);
}

// Round 6
// 587.403 us; speedup vs baseline: 1.1804x; 1.1775x over previous
//
#include <hip/hip_runtime.h>
#include <hip/hip_fp16.h>

#define BN_EPS 1e-5f

__device__ __forceinline__ float4 f4zero() { return make_float4(0.f, 0.f, 0.f, 0.f); }

// ---------------- graph preprocessing ----------------

// histogram AND per-edge within-node rank (the atomic's return value, stored
// coalesced). This removes the need for any atomic in the scatter kernel:
// slot = offs[dst] + rank.
__global__ __launch_bounds__(256) void k_hist(const int* __restrict__ dst,
                                              int* __restrict__ counts,
                                              int* __restrict__ rank, int e) {
    int i = blockIdx.x * 256 + threadIdx.x;
    if (i < e) rank[i] = atomicAdd(&counts[dst[i]], 1);
}

__global__ __launch_bounds__(256) void k_dinv(const int* __restrict__ counts,
                                              float* __restrict__ dinv, int n) {
    int i = blockIdx.x * 256 + threadIdx.x;
    if (i < n) dinv[i] = rsqrtf((float)(counts[i] + 1));  // +1 = self loop, always > 0
}

// exclusive scan of PADDED counts ((c+7)&~7) so every node's edge list is a
// multiple of 8 records and 32 B aligned.
__global__ __launch_bounds__(1024) void k_scan_block(const int* __restrict__ counts,
                                                     int* __restrict__ offs,
                                                     int* __restrict__ partials, int n) {
    __shared__ int s[1024];
    int t = threadIdx.x;
    int gid = blockIdx.x * 1024 + t;
    int c = (gid < n) ? counts[gid] : 0;
    int v = (c + 7) & ~7;
    int x = v;
    s[t] = x;
    __syncthreads();
    for (int d = 1; d < 1024; d <<= 1) {
        int y = (t >= d) ? s[t - d] : 0;
        __syncthreads();
        x += y;
        s[t] = x;
        __syncthreads();
    }
    if (gid < n) offs[gid] = x - v;               // exclusive scan within block
    if (t == 1023) partials[blockIdx.x] = x;      // block total
}

// parallel scan of block partials (nb <= 1024). partials[i] -> exclusive, partials[nb] = total
__global__ __launch_bounds__(1024) void k_scan_partials(int* __restrict__ partials, int nb) {
    __shared__ int s[1024];
    int t = threadIdx.x;
    int v = (t < nb) ? partials[t] : 0;
    int x = v;
    s[t] = x;
    __syncthreads();
    for (int d = 1; d < 1024; d <<= 1) {
        int y = (t >= d) ? s[t - d] : 0;
        __syncthreads();
        x += y;
        s[t] = x;
        __syncthreads();
    }
    if (t < nb) partials[t] = x - v;
    if (t == nb - 1) partials[nb] = x;
}

__global__ __launch_bounds__(256) void k_scan_add(int* __restrict__ offs,
                                                  const int* __restrict__ partials, int n) {
    int gid = blockIdx.x * 256 + threadIdx.x;
    if (gid < n) offs[gid] += partials[gid >> 10];
    if (gid == 0) offs[n] = partials[(n + 1023) >> 10];
}

// prefill er with the dummy (zero-row) index so padding slots gather zeros
__global__ __launch_bounds__(256) void k_fill(int4* __restrict__ er4, int val, int m4) {
    int i = blockIdx.x * 256 + threadIdx.x;
    if (i < m4) er4[i] = make_int4(val, val, val, val);
}

// scatter WITHOUT atomics: slot = offs[dst] + rank (rank captured in k_hist).
// Stores are fire-and-forget (no return value), so nothing waits on the
// random addresses except the end-of-kernel drain. 4 edges/thread, int4 reads.
// (R4 lesson kept: no nontemporal stores — they defeat L2 write combining.)
__global__ __launch_bounds__(256) void k_scatter(const int* __restrict__ src,
                                                 const int* __restrict__ dst,
                                                 const int* __restrict__ rank,
                                                 const int* __restrict__ offs,
                                                 int* __restrict__ er, int e) {
    int base = (blockIdx.x * 256 + threadIdx.x) * 4;
    if (base + 3 < e) {
        int4 s4 = *(const int4*)(src + base);
        int4 d4 = *(const int4*)(dst + base);
        int4 r4 = *(const int4*)(rank + base);
        int o0 = offs[d4.x];
        int o1 = offs[d4.y];
        int o2 = offs[d4.z];
        int o3 = offs[d4.w];
        er[o0 + r4.x] = s4.x;
        er[o1 + r4.y] = s4.y;
        er[o2 + r4.z] = s4.z;
        er[o3 + r4.w] = s4.w;
    } else {
        for (int i = base; i < e; ++i) {
            er[offs[dst[i]] + rank[i]] = src[i];
        }
    }
}

// ---------------- GEMM: C[n,128](f16) = (A[n,128](f32) @ W[128,128](f32)) * dinv[row] ----
// dinv[row] folded into the stored row => all edge weights in aggregation become 1.

__global__ __launch_bounds__(256) void k_gemm128(const float* __restrict__ A,
                                                 const float* __restrict__ W,
                                                 const float* __restrict__ dinv,
                                                 uint2* __restrict__ C, int n) {
    __shared__ float Ws[64 * 128];   // 32 KB: one 64-row chunk of W
    __shared__ float As[64 * 128];   // 32 KB: A tile, full K=128
    int tid = threadIdx.x;
    int row0 = blockIdx.x * 64;

    {   // stage A tile (2048 float4, 8 per thread)
        const float4* Av = (const float4*)A;
        float4* Asv = (float4*)As;
#pragma unroll
        for (int i = 0; i < 8; ++i) {
            int idx = tid + 256 * i;          // 0..2047
            int r = idx >> 5;                 // row in tile
            int row = row0 + r;
            Asv[idx] = (row < n) ? Av[row * 32 + (idx & 31)] : f4zero();
        }
    }

    int cg = tid & 31;     // cols 4*cg .. 4*cg+3
    int rid = tid >> 5;    // rows rid*8 .. rid*8+7
    float4 acc[8];
#pragma unroll
    for (int r = 0; r < 8; ++r) acc[r] = f4zero();

    const float4* Asv = (const float4*)As;
    const float4* Wsv = (const float4*)Ws;
    const float4* Wv = (const float4*)W;

    for (int kh = 0; kh < 2; ++kh) {
        __syncthreads();
        {   // stage W rows [kh*64, kh*64+64): 2048 float4
            float4* Wsw = (float4*)Ws;
#pragma unroll
            for (int i = 0; i < 8; ++i) {
                int idx = tid + 256 * i;
                Wsw[idx] = Wv[kh * 2048 + idx];
            }
        }
        __syncthreads();
#pragma unroll 4
        for (int k4 = 0; k4 < 16; ++k4) {   // local k-quad within chunk
            float4 w0 = Wsv[(4 * k4 + 0) * 32 + cg];
            float4 w1 = Wsv[(4 * k4 + 1) * 32 + cg];
            float4 w2 = Wsv[(4 * k4 + 2) * 32 + cg];
            float4 w3 = Wsv[(4 * k4 + 3) * 32 + cg];
#pragma unroll
            for (int r = 0; r < 8; ++r) {
                float4 a = Asv[(rid * 8 + r) * 32 + (kh * 16 + k4)];
                acc[r].x += a.x * w0.x; acc[r].x += a.y * w1.x; acc[r].x += a.z * w2.x; acc[r].x += a.w * w3.x;
                acc[r].y += a.x * w0.y; acc[r].y += a.y * w1.y; acc[r].y += a.z * w2.y; acc[r].y += a.w * w3.y;
                acc[r].z += a.x * w0.z; acc[r].z += a.y * w1.z; acc[r].z += a.z * w2.z; acc[r].z += a.w * w3.z;
                acc[r].w += a.x * w0.w; acc[r].w += a.y * w1.w; acc[r].w += a.z * w2.w; acc[r].w += a.w * w3.w;
            }
        }
    }

#pragma unroll
    for (int r = 0; r < 8; ++r) {
        int row = row0 + rid * 8 + r;
        if (row < n) {
            float di = dinv[row];
            __half2 p0 = __floats2half2_rn(acc[r].x * di, acc[r].y * di);
            __half2 p1 = __floats2half2_rn(acc[r].z * di, acc[r].w * di);
            uint2 u;
            u.x = *(unsigned int*)&p0;
            u.y = *(unsigned int*)&p1;
            C[row * 32 + cg] = u;   // row = 32 x uint2 = 128 halfs = 256 B
        }
    }
}

// ---------------- CSR aggregation + bias + ReLU + BN (+ optional classifier) ----------------
// 32 lanes per node; gathers pre-scaled f16 rows, unweighted f32 accumulate,
// final scale by dinv[node]. Edge lists padded to x8 with zero-row index.

__device__ __forceinline__ void acc_row(float4& acc, uint2 q) {
    float2 f01 = __half22float2(*(__half2*)&q.x);
    float2 f23 = __half22float2(*(__half2*)&q.y);
    acc.x += f01.x; acc.y += f01.y; acc.z += f23.x; acc.w += f23.y;
}

template <bool FUSE_CLS>
__global__ __launch_bounds__(256) void k_aggregate(const uint2* __restrict__ Ah,
                                                   const int* __restrict__ offs,
                                                   const int* __restrict__ er,
                                                   const float* __restrict__ dinv,
                                                   const float* __restrict__ bias,
                                                   const float* __restrict__ g,
                                                   const float* __restrict__ be,
                                                   const float* __restrict__ rm,
                                                   const float* __restrict__ rv,
                                                   float4* __restrict__ Hout,
                                                   const float* __restrict__ Wc,
                                                   const float* __restrict__ bc,
                                                   float* __restrict__ out, int n) {
    int lane = threadIdx.x & 31;
    int node = blockIdx.x * 8 + (threadIdx.x >> 5);
    if (node >= n) return;

    float4 acc = f4zero();
    acc_row(acc, Ah[node * 32 + lane]);           // self loop (weight folds to dinv^2)

    int e0 = offs[node], e1 = offs[node + 1];
    for (int e = e0; e < e1; e += 8) {            // always full, aligned batches of 8
        int4 ra = *(const int4*)(er + e);
        int4 rb = *(const int4*)(er + e + 4);
        uint2 v0 = Ah[ra.x * 32 + lane];
        uint2 v1 = Ah[ra.y * 32 + lane];
        uint2 v2 = Ah[ra.z * 32 + lane];
        uint2 v3 = Ah[ra.w * 32 + lane];
        uint2 v4 = Ah[rb.x * 32 + lane];
        uint2 v5 = Ah[rb.y * 32 + lane];
        uint2 v6 = Ah[rb.z * 32 + lane];
        uint2 v7 = Ah[rb.w * 32 + lane];
        acc_row(acc, v0); acc_row(acc, v1); acc_row(acc, v2); acc_row(acc, v3);
        acc_row(acc, v4); acc_row(acc, v5); acc_row(acc, v6); acc_row(acc, v7);
    }

    float di = dinv[node];
    acc.x *= di; acc.y *= di; acc.z *= di; acc.w *= di;

    float4 b4  = ((const float4*)bias)[lane];
    float4 g4  = ((const float4*)g)[lane];
    float4 be4 = ((const float4*)be)[lane];
    float4 rm4 = ((const float4*)rm)[lane];
    float4 rv4 = ((const float4*)rv)[lane];

    float4 o;
    float v;
    v = fmaxf(acc.x + b4.x, 0.f); o.x = (v - rm4.x) * rsqrtf(rv4.x + BN_EPS) * g4.x + be4.x;
    v = fmaxf(acc.y + b4.y, 0.f); o.y = (v - rm4.y) * rsqrtf(rv4.y + BN_EPS) * g4.y + be4.y;
    v = fmaxf(acc.z + b4.z, 0.f); o.z = (v - rm4.z) * rsqrtf(rv4.z + BN_EPS) * g4.z + be4.z;
    v = fmaxf(acc.w + b4.w, 0.f); o.w = (v - rm4.w) * rsqrtf(rv4.w + BN_EPS) * g4.w + be4.w;

    if (!FUSE_CLS) {
        Hout[node * 32 + lane] = o;
    } else {
        const float4* Wv = (const float4*)Wc;       // Wc row-major [128][2]
        float4 w01 = Wv[2 * lane];                  // (Wc[k][0],Wc[k][1],Wc[k+1][0],Wc[k+1][1])
        float4 w23 = Wv[2 * lane + 1];
        float p0 = o.x * w01.x + o.y * w01.z + o.z * w23.x + o.w * w23.z;
        float p1 = o.x * w01.y + o.y * w01.w + o.z * w23.y + o.w * w23.w;
#pragma unroll
        for (int d = 16; d >= 1; d >>= 1) {
            p0 += __shfl_down(p0, d, 32);
            p1 += __shfl_down(p1, d, 32);
        }
        if (lane == 0) {
            out[node * 2 + 0] = p0 + bc[0];
            out[node * 2 + 1] = p1 + bc[1];
        }
    }
}

// ---------------- launch ----------------

extern "C" void kernel_launch(void* const* d_in, const int* in_sizes, int n_in,
                              void* d_out, int out_size, void* d_ws, size_t ws_size,
                              hipStream_t stream) {
    const float* x   = (const float*)d_in[0];
    const int*   ei  = (const int*)d_in[1];    // [2,E] int32 (JAX demotes int64)
    const float* W1  = (const float*)d_in[2];
    const float* b1  = (const float*)d_in[3];
    const float* W2  = (const float*)d_in[4];
    const float* b2  = (const float*)d_in[5];
    const float* W3  = (const float*)d_in[6];
    const float* b3  = (const float*)d_in[7];
    const float* g1  = (const float*)d_in[8];
    const float* be1 = (const float*)d_in[9];
    const float* rm1 = (const float*)d_in[10];
    const float* rv1 = (const float*)d_in[11];
    const float* g2  = (const float*)d_in[12];
    const float* be2 = (const float*)d_in[13];
    const float* rm2 = (const float*)d_in[14];
    const float* rv2 = (const float*)d_in[15];
    const float* g3  = (const float*)d_in[16];
    const float* be3 = (const float*)d_in[17];
    const float* rm3 = (const float*)d_in[18];
    const float* rv3 = (const float*)d_in[19];
    const float* Wc  = (const float*)d_in[20];
    const float* bc  = (const float*)d_in[21];
    float* out = (float*)d_out;

    int n = in_sizes[0] / 128;
    int e = in_sizes[1] / 2;
    const int* src = ei;
    const int* dst = ei + e;

    char* ws = (char*)d_ws;
    size_t off = 0;
    auto alloc = [&](size_t bytes) -> char* {
        char* p = ws + off;
        off += (bytes + 255) & ~(size_t)255;
        return p;
    };
    int erCap = e + 8 * n;                                    // padded CSR capacity
    uint2* bufA   = (uint2*)alloc((size_t)(n + 1) * 128 * 2); // GEMM out f16, +1 zero row
    float* bufH   = (float*)alloc((size_t)n * 128 * 4);       // aggregated hidden, f32
    float* dinv   = (float*)alloc((size_t)n * 4);
    int*   counts = (int*)  alloc((size_t)n * 4);
    int*   offs   = (int*)  alloc((size_t)(n + 1) * 4);
    int*   rank   = (int*)  alloc((size_t)e * 4);
    int*   parts  = (int*)  alloc(8192);
    int*   er     = (int*)  alloc((size_t)erCap * 4);
    (void)ws_size; (void)n_in; (void)out_size;

    hipMemsetAsync(counts, 0, (size_t)n * 4, stream);
    hipMemsetAsync(bufA + (size_t)n * 32, 0, 256, stream);   // zero row n (padding target)

    int gE = (e + 255) / 256;
    int gN = (n + 255) / 256;
    int nb = (n + 1023) / 1024;
    int m4 = erCap / 4;

    k_hist<<<gE, 256, 0, stream>>>(dst, counts, rank, e);
    k_dinv<<<gN, 256, 0, stream>>>(counts, dinv, n);
    k_scan_block<<<nb, 1024, 0, stream>>>(counts, offs, parts, n);
    k_scan_partials<<<1, 1024, 0, stream>>>(parts, nb);
    k_scan_add<<<gN, 256, 0, stream>>>(offs, parts, n);
    k_fill<<<(m4 + 255) / 256, 256, 0, stream>>>((int4*)er, n, m4);
    int gS = (e / 4 + 255) / 256 + 1;    // 4 edges per thread
    k_scatter<<<gS, 256, 0, stream>>>(src, dst, rank, offs, er, e);

    int gGemm = (n + 63) / 64;
    int gAgg  = (n + 7) / 8;

    k_gemm128<<<gGemm, 256, 0, stream>>>(x, W1, dinv, bufA, n);
    k_aggregate<false><<<gAgg, 256, 0, stream>>>(bufA, offs, er, dinv,
                                                 b1, g1, be1, rm1, rv1, (float4*)bufH,
                                                 nullptr, nullptr, nullptr, n);

    k_gemm128<<<gGemm, 256, 0, stream>>>(bufH, W2, dinv, bufA, n);
    k_aggregate<false><<<gAgg, 256, 0, stream>>>(bufA, offs, er, dinv,
                                                 b2, g2, be2, rm2, rv2, (float4*)bufH,
                                                 nullptr, nullptr, nullptr, n);

    k_gemm128<<<gGemm, 256, 0, stream>>>(bufH, W3, dinv, bufA, n);
    k_aggregate<true><<<gAgg, 256, 0, stream>>>(bufA, offs, er, dinv,
                                                b3, g3, be3, rm3, rv3, nullptr,
                                                Wc, bc, out, n);
}

// Round 7
// 538.011 us; speedup vs baseline: 1.2888x; 1.0918x over previous
//
#include <hip/hip_runtime.h>
#include <hip/hip_fp16.h>

#define BN_EPS 1e-5f
#define CHUNK 4096            // edges per bucketing block (A and B must match)

__device__ __forceinline__ float4 f4zero() { return make_float4(0.f, 0.f, 0.f, 0.f); }

// ---------------- bucket-sort CSR build (no device-scope returning atomics) ----------------
// Bucket = dst >> 8 (256 nodes per bucket). All returning atomics are LDS-scope.

// A: per-chunk histogram over buckets -> tableT[bucket * nA + chunk]
__global__ __launch_bounds__(256) void k_bucket_hist(const int* __restrict__ dst,
                                                     int* __restrict__ tableT,
                                                     int nA, int nbuck, int e) {
    __shared__ int h[1024];
    int blk = blockIdx.x, tid = threadIdx.x;
    for (int k = tid; k < 1024; k += 256) h[k] = 0;
    __syncthreads();
    int base = blk * CHUNK;
    if (base + CHUNK <= e && (e & 3) == 0) {
        const int4* d4 = (const int4*)(dst + base);
#pragma unroll
        for (int t = 0; t < 4; ++t) {
            int4 d = d4[t * 256 + tid];
            atomicAdd(&h[d.x >> 8], 1);
            atomicAdd(&h[d.y >> 8], 1);
            atomicAdd(&h[d.z >> 8], 1);
            atomicAdd(&h[d.w >> 8], 1);
        }
    } else {
        for (int i = base + tid; i < e && i < base + CHUNK; i += 256)
            atomicAdd(&h[dst[i] >> 8], 1);
    }
    __syncthreads();
    for (int k = tid; k < nbuck; k += 256)
        tableT[(size_t)k * nA + blk] = h[k];
}

// B: scatter edges into bucket-grouped COO using LDS cursors (LDS returning atomics)
__global__ __launch_bounds__(256) void k_bucket_scatter(const int* __restrict__ src,
                                                        const int* __restrict__ dst,
                                                        const int* __restrict__ tableT,
                                                        int2* __restrict__ bed,
                                                        int nA, int nbuck, int e) {
    __shared__ int cur[1024];
    int blk = blockIdx.x, tid = threadIdx.x;
    for (int k = tid; k < nbuck; k += 256)
        cur[k] = tableT[(size_t)k * nA + blk];
    __syncthreads();
    int base = blk * CHUNK;
    if (base + CHUNK <= e && (e & 3) == 0) {
        const int4* s4 = (const int4*)(src + base);
        const int4* d4 = (const int4*)(dst + base);
#pragma unroll
        for (int t = 0; t < 4; ++t) {
            int4 s = s4[t * 256 + tid];
            int4 d = d4[t * 256 + tid];
            int p0 = atomicAdd(&cur[d.x >> 8], 1); bed[p0] = make_int2(s.x, d.x);
            int p1 = atomicAdd(&cur[d.y >> 8], 1); bed[p1] = make_int2(s.y, d.y);
            int p2 = atomicAdd(&cur[d.z >> 8], 1); bed[p2] = make_int2(s.z, d.z);
            int p3 = atomicAdd(&cur[d.w >> 8], 1); bed[p3] = make_int2(s.w, d.w);
        }
    } else {
        for (int i = base + tid; i < e && i < base + CHUNK; i += 256) {
            int d = dst[i];
            int p = atomicAdd(&cur[d >> 8], 1);
            bed[p] = make_int2(src[i], d);
        }
    }
}

// C: one block per bucket: per-node counts + per-edge rank via LDS counters.
// counts written with plain stores (no global atomics anywhere).
__global__ __launch_bounds__(256) void k_bucket_rank(const int2* __restrict__ bed,
                                                     const int* __restrict__ tableT,
                                                     int* __restrict__ brank,
                                                     int* __restrict__ counts,
                                                     int nA, int nbuck, int n, int e) {
    __shared__ int lcnt[256];
    int b = blockIdx.x, tid = threadIdx.x;
    lcnt[tid] = 0;
    __syncthreads();
    int start = tableT[(size_t)b * nA];
    int end = (b + 1 < nbuck) ? tableT[(size_t)(b + 1) * nA] : e;
    for (int i = start + tid; i < end; i += 256) {
        int2 q = bed[i];
        brank[i] = atomicAdd(&lcnt[q.y & 255], 1);
    }
    __syncthreads();
    int node = (b << 8) + tid;
    if (node < n) counts[node] = lcnt[tid];
}

__global__ __launch_bounds__(256) void k_dinv(const int* __restrict__ counts,
                                              float* __restrict__ dinv, int n) {
    int i = blockIdx.x * 256 + threadIdx.x;
    if (i < n) dinv[i] = rsqrtf((float)(counts[i] + 1));  // +1 = self loop, always > 0
}

// exclusive scan; PAD8 pads each count to a multiple of 8 (for CSR offs).
template <bool PAD8>
__global__ __launch_bounds__(1024) void k_scan_block(const int* __restrict__ counts,
                                                     int* __restrict__ offs,
                                                     int* __restrict__ partials, int len) {
    __shared__ int s[1024];
    int t = threadIdx.x;
    int gid = blockIdx.x * 1024 + t;
    int c = (gid < len) ? counts[gid] : 0;
    int v = PAD8 ? ((c + 7) & ~7) : c;
    int x = v;
    s[t] = x;
    __syncthreads();
    for (int d = 1; d < 1024; d <<= 1) {
        int y = (t >= d) ? s[t - d] : 0;
        __syncthreads();
        x += y;
        s[t] = x;
        __syncthreads();
    }
    if (gid < len) offs[gid] = x - v;
    if (t == 1023) partials[blockIdx.x] = x;
}

__global__ __launch_bounds__(1024) void k_scan_partials(int* __restrict__ partials, int nb) {
    __shared__ int s[1024];
    int t = threadIdx.x;
    int v = (t < nb) ? partials[t] : 0;
    int x = v;
    s[t] = x;
    __syncthreads();
    for (int d = 1; d < 1024; d <<= 1) {
        int y = (t >= d) ? s[t - d] : 0;
        __syncthreads();
        x += y;
        s[t] = x;
        __syncthreads();
    }
    if (t < nb) partials[t] = x - v;
    if (t == nb - 1) partials[nb] = x;
}

__global__ __launch_bounds__(256) void k_scan_add(int* __restrict__ offs,
                                                  const int* __restrict__ partials, int len) {
    int gid = blockIdx.x * 256 + threadIdx.x;
    if (gid < len) offs[gid] += partials[gid >> 10];
    if (gid == 0) offs[len] = partials[(len + 1023) >> 10];
}

// prefill er with the dummy (zero-row) index so padding slots gather zeros
__global__ __launch_bounds__(256) void k_fill(int4* __restrict__ er4, int val, int m4) {
    int i = blockIdx.x * 256 + threadIdx.x;
    if (i < m4) er4[i] = make_int4(val, val, val, val);
}

// E: final CSR place. Edges are bucket-grouped, so offs gathers and er writes
// stay within a 256-node window -> L2-local. No atomics.
__global__ __launch_bounds__(256) void k_place2(const int2* __restrict__ bed,
                                                const int* __restrict__ brank,
                                                const int* __restrict__ offs,
                                                int* __restrict__ er, int e) {
    int i = (blockIdx.x * 256 + threadIdx.x) * 2;
    if (i + 1 < e) {
        int4 q = *(const int4*)(bed + i);      // (src0,dst0,src1,dst1)
        int2 r = *(const int2*)(brank + i);
        er[offs[q.y] + r.x] = q.x;
        er[offs[q.w] + r.y] = q.z;
    } else if (i < e) {
        int2 q = bed[i];
        er[offs[q.y] + brank[i]] = q.x;
    }
}

// ---------------- GEMM: C[n,128](f16) = (A[n,128](f32) @ W[128,128](f32)) * dinv[row] ----

__global__ __launch_bounds__(256) void k_gemm128(const float* __restrict__ A,
                                                 const float* __restrict__ W,
                                                 const float* __restrict__ dinv,
                                                 uint2* __restrict__ C, int n) {
    __shared__ float Ws[64 * 128];
    __shared__ float As[64 * 128];
    int tid = threadIdx.x;
    int row0 = blockIdx.x * 64;

    {
        const float4* Av = (const float4*)A;
        float4* Asv = (float4*)As;
#pragma unroll
        for (int i = 0; i < 8; ++i) {
            int idx = tid + 256 * i;
            int r = idx >> 5;
            int row = row0 + r;
            Asv[idx] = (row < n) ? Av[row * 32 + (idx & 31)] : f4zero();
        }
    }

    int cg = tid & 31;
    int rid = tid >> 5;
    float4 acc[8];
#pragma unroll
    for (int r = 0; r < 8; ++r) acc[r] = f4zero();

    const float4* Asv = (const float4*)As;
    const float4* Wsv = (const float4*)Ws;
    const float4* Wv = (const float4*)W;

    for (int kh = 0; kh < 2; ++kh) {
        __syncthreads();
        {
            float4* Wsw = (float4*)Ws;
#pragma unroll
            for (int i = 0; i < 8; ++i) {
                int idx = tid + 256 * i;
                Wsw[idx] = Wv[kh * 2048 + idx];
            }
        }
        __syncthreads();
#pragma unroll 4
        for (int k4 = 0; k4 < 16; ++k4) {
            float4 w0 = Wsv[(4 * k4 + 0) * 32 + cg];
            float4 w1 = Wsv[(4 * k4 + 1) * 32 + cg];
            float4 w2 = Wsv[(4 * k4 + 2) * 32 + cg];
            float4 w3 = Wsv[(4 * k4 + 3) * 32 + cg];
#pragma unroll
            for (int r = 0; r < 8; ++r) {
                float4 a = Asv[(rid * 8 + r) * 32 + (kh * 16 + k4)];
                acc[r].x += a.x * w0.x; acc[r].x += a.y * w1.x; acc[r].x += a.z * w2.x; acc[r].x += a.w * w3.x;
                acc[r].y += a.x * w0.y; acc[r].y += a.y * w1.y; acc[r].y += a.z * w2.y; acc[r].y += a.w * w3.y;
                acc[r].z += a.x * w0.z; acc[r].z += a.y * w1.z; acc[r].z += a.z * w2.z; acc[r].z += a.w * w3.z;
                acc[r].w += a.x * w0.w; acc[r].w += a.y * w1.w; acc[r].w += a.z * w2.w; acc[r].w += a.w * w3.w;
            }
        }
    }

#pragma unroll
    for (int r = 0; r < 8; ++r) {
        int row = row0 + rid * 8 + r;
        if (row < n) {
            float di = dinv[row];
            __half2 p0 = __floats2half2_rn(acc[r].x * di, acc[r].y * di);
            __half2 p1 = __floats2half2_rn(acc[r].z * di, acc[r].w * di);
            uint2 u;
            u.x = *(unsigned int*)&p0;
            u.y = *(unsigned int*)&p1;
            C[row * 32 + cg] = u;
        }
    }
}

// ---------------- CSR aggregation + bias + ReLU + BN (+ optional classifier) ----------------

__device__ __forceinline__ void acc_row(float4& acc, uint2 q) {
    float2 f01 = __half22float2(*(__half2*)&q.x);
    float2 f23 = __half22float2(*(__half2*)&q.y);
    acc.x += f01.x; acc.y += f01.y; acc.z += f23.x; acc.w += f23.y;
}

template <bool FUSE_CLS>
__global__ __launch_bounds__(256) void k_aggregate(const uint2* __restrict__ Ah,
                                                   const int* __restrict__ offs,
                                                   const int* __restrict__ er,
                                                   const float* __restrict__ dinv,
                                                   const float* __restrict__ bias,
                                                   const float* __restrict__ g,
                                                   const float* __restrict__ be,
                                                   const float* __restrict__ rm,
                                                   const float* __restrict__ rv,
                                                   float4* __restrict__ Hout,
                                                   const float* __restrict__ Wc,
                                                   const float* __restrict__ bc,
                                                   float* __restrict__ out, int n) {
    int lane = threadIdx.x & 31;
    int node = blockIdx.x * 8 + (threadIdx.x >> 5);
    if (node >= n) return;

    float4 acc = f4zero();
    acc_row(acc, Ah[node * 32 + lane]);           // self loop

    int e0 = offs[node], e1 = offs[node + 1];
    for (int e = e0; e < e1; e += 8) {
        int4 ra = *(const int4*)(er + e);
        int4 rb = *(const int4*)(er + e + 4);
        uint2 v0 = Ah[ra.x * 32 + lane];
        uint2 v1 = Ah[ra.y * 32 + lane];
        uint2 v2 = Ah[ra.z * 32 + lane];
        uint2 v3 = Ah[ra.w * 32 + lane];
        uint2 v4 = Ah[rb.x * 32 + lane];
        uint2 v5 = Ah[rb.y * 32 + lane];
        uint2 v6 = Ah[rb.z * 32 + lane];
        uint2 v7 = Ah[rb.w * 32 + lane];
        acc_row(acc, v0); acc_row(acc, v1); acc_row(acc, v2); acc_row(acc, v3);
        acc_row(acc, v4); acc_row(acc, v5); acc_row(acc, v6); acc_row(acc, v7);
    }

    float di = dinv[node];
    acc.x *= di; acc.y *= di; acc.z *= di; acc.w *= di;

    float4 b4  = ((const float4*)bias)[lane];
    float4 g4  = ((const float4*)g)[lane];
    float4 be4 = ((const float4*)be)[lane];
    float4 rm4 = ((const float4*)rm)[lane];
    float4 rv4 = ((const float4*)rv)[lane];

    float4 o;
    float v;
    v = fmaxf(acc.x + b4.x, 0.f); o.x = (v - rm4.x) * rsqrtf(rv4.x + BN_EPS) * g4.x + be4.x;
    v = fmaxf(acc.y + b4.y, 0.f); o.y = (v - rm4.y) * rsqrtf(rv4.y + BN_EPS) * g4.y + be4.y;
    v = fmaxf(acc.z + b4.z, 0.f); o.z = (v - rm4.z) * rsqrtf(rv4.z + BN_EPS) * g4.z + be4.z;
    v = fmaxf(acc.w + b4.w, 0.f); o.w = (v - rm4.w) * rsqrtf(rv4.w + BN_EPS) * g4.w + be4.w;

    if (!FUSE_CLS) {
        Hout[node * 32 + lane] = o;
    } else {
        const float4* Wv = (const float4*)Wc;
        float4 w01 = Wv[2 * lane];
        float4 w23 = Wv[2 * lane + 1];
        float p0 = o.x * w01.x + o.y * w01.z + o.z * w23.x + o.w * w23.z;
        float p1 = o.x * w01.y + o.y * w01.w + o.z * w23.y + o.w * w23.w;
#pragma unroll
        for (int d = 16; d >= 1; d >>= 1) {
            p0 += __shfl_down(p0, d, 32);
            p1 += __shfl_down(p1, d, 32);
        }
        if (lane == 0) {
            out[node * 2 + 0] = p0 + bc[0];
            out[node * 2 + 1] = p1 + bc[1];
        }
    }
}

// ---------------- launch ----------------

extern "C" void kernel_launch(void* const* d_in, const int* in_sizes, int n_in,
                              void* d_out, int out_size, void* d_ws, size_t ws_size,
                              hipStream_t stream) {
    const float* x   = (const float*)d_in[0];
    const int*   ei  = (const int*)d_in[1];    // [2,E] int32 (JAX demotes int64)
    const float* W1  = (const float*)d_in[2];
    const float* b1  = (const float*)d_in[3];
    const float* W2  = (const float*)d_in[4];
    const float* b2  = (const float*)d_in[5];
    const float* W3  = (const float*)d_in[6];
    const float* b3  = (const float*)d_in[7];
    const float* g1  = (const float*)d_in[8];
    const float* be1 = (const float*)d_in[9];
    const float* rm1 = (const float*)d_in[10];
    const float* rv1 = (const float*)d_in[11];
    const float* g2  = (const float*)d_in[12];
    const float* be2 = (const float*)d_in[13];
    const float* rm2 = (const float*)d_in[14];
    const float* rv2 = (const float*)d_in[15];
    const float* g3  = (const float*)d_in[16];
    const float* be3 = (const float*)d_in[17];
    const float* rm3 = (const float*)d_in[18];
    const float* rv3 = (const float*)d_in[19];
    const float* Wc  = (const float*)d_in[20];
    const float* bc  = (const float*)d_in[21];
    float* out = (float*)d_out;

    int n = in_sizes[0] / 128;
    int e = in_sizes[1] / 2;
    const int* src = ei;
    const int* dst = ei + e;

    char* ws = (char*)d_ws;
    size_t off = 0;
    auto alloc = [&](size_t bytes) -> char* {
        char* p = ws + off;
        off += (bytes + 255) & ~(size_t)255;
        return p;
    };
    int erCap = e + 8 * n;                                    // padded CSR capacity
    uint2* bufA   = (uint2*)alloc((size_t)(n + 1) * 128 * 2); // GEMM out f16, +1 zero row
    float* bufH   = (float*)alloc((size_t)n * 128 * 4);       // aggregated hidden, f32
    float* dinv   = (float*)alloc((size_t)n * 4);
    int*   counts = (int*)  alloc((size_t)n * 4);
    int*   offs   = (int*)  alloc((size_t)(n + 1) * 4);
    int*   parts  = (int*)  alloc(8192);
    int*   er     = (int*)  alloc((size_t)erCap * 4);
    (void)ws_size; (void)n_in; (void)out_size;

    // prep scratch aliased into bufH (dead until first aggregate)
    int nA    = (e + CHUNK - 1) / CHUNK;
    int nbuck = (n + 255) >> 8;
    int tlen  = nbuck * nA;
    {
        char* p = (char*)bufH;
        size_t po = 0;
        auto palloc = [&](size_t bytes) -> char* {
            char* q = p + po;
            po += (bytes + 255) & ~(size_t)255;
            return q;
        };
        int2* bed    = (int2*)palloc((size_t)e * 8);
        int*  brank  = (int*) palloc((size_t)e * 4);
        int*  tableT = (int*) palloc((size_t)(tlen + 1) * 4);

        hipMemsetAsync(bufA + (size_t)n * 32, 0, 256, stream);  // zero row n (padding target)

        int gN  = (n + 255) / 256;
        int nb  = (n + 1023) / 1024;
        int nbT = (tlen + 1023) / 1024;
        int m4  = erCap / 4;

        k_bucket_hist<<<nA, 256, 0, stream>>>(dst, tableT, nA, nbuck, e);
        k_scan_block<false><<<nbT, 1024, 0, stream>>>(tableT, tableT, parts, tlen);
        k_scan_partials<<<1, 1024, 0, stream>>>(parts, nbT);
        k_scan_add<<<(tlen + 255) / 256, 256, 0, stream>>>(tableT, parts, tlen);
        k_bucket_scatter<<<nA, 256, 0, stream>>>(src, dst, tableT, bed, nA, nbuck, e);
        k_bucket_rank<<<nbuck, 256, 0, stream>>>(bed, tableT, brank, counts, nA, nbuck, n, e);
        k_dinv<<<gN, 256, 0, stream>>>(counts, dinv, n);
        k_scan_block<true><<<nb, 1024, 0, stream>>>(counts, offs, parts, n);
        k_scan_partials<<<1, 1024, 0, stream>>>(parts, nb);
        k_scan_add<<<gN, 256, 0, stream>>>(offs, parts, n);
        k_fill<<<(m4 + 255) / 256, 256, 0, stream>>>((int4*)er, n, m4);
        k_place2<<<((e + 1) / 2 + 255) / 256, 256, 0, stream>>>(bed, brank, offs, er, e);
    }

    int gGemm = (n + 63) / 64;
    int gAgg  = (n + 7) / 8;

    k_gemm128<<<gGemm, 256, 0, stream>>>(x, W1, dinv, bufA, n);
    k_aggregate<false><<<gAgg, 256, 0, stream>>>(bufA, offs, er, dinv,
                                                 b1, g1, be1, rm1, rv1, (float4*)bufH,
                                                 nullptr, nullptr, nullptr, n);

    k_gemm128<<<gGemm, 256, 0, stream>>>(bufH, W2, dinv, bufA, n);
    k_aggregate<false><<<gAgg, 256, 0, stream>>>(bufA, offs, er, dinv,
                                                 b2, g2, be2, rm2, rv2, (float4*)bufH,
                                                 nullptr, nullptr, nullptr, n);

    k_gemm128<<<gGemm, 256, 0, stream>>>(bufH, W3, dinv, bufA, n);
    k_aggregate<true><<<gAgg, 256, 0, stream>>>(bufA, offs, er, dinv,
                                                b3, g3, be3, rm3, rv3, nullptr,
                                                Wc, bc, out, n);
}

// Round 8
// 412.154 us; speedup vs baseline: 1.6823x; 1.3054x over previous
//
#include <hip/hip_runtime.h>
#include <hip/hip_fp16.h>

#define BN_EPS 1e-5f
#define CHUNK 4096            // edges per bucketing block (A and B must match)

typedef _Float16 half8 __attribute__((ext_vector_type(8)));
typedef float f32x4 __attribute__((ext_vector_type(4)));

__device__ __forceinline__ float4 f4zero() { return make_float4(0.f, 0.f, 0.f, 0.f); }

// ---------------- bucket-sort CSR build (no device-scope returning atomics) ----------------
// Bucket = dst >> 8 (256 nodes per bucket). All returning atomics are LDS-scope.

__global__ __launch_bounds__(256) void k_bucket_hist(const int* __restrict__ dst,
                                                     int* __restrict__ tableT,
                                                     int nA, int nbuck, int e) {
    __shared__ int h[1024];
    int blk = blockIdx.x, tid = threadIdx.x;
    for (int k = tid; k < 1024; k += 256) h[k] = 0;
    __syncthreads();
    int base = blk * CHUNK;
    if (base + CHUNK <= e && (e & 3) == 0) {
        const int4* d4 = (const int4*)(dst + base);
#pragma unroll
        for (int t = 0; t < 4; ++t) {
            int4 d = d4[t * 256 + tid];
            atomicAdd(&h[d.x >> 8], 1);
            atomicAdd(&h[d.y >> 8], 1);
            atomicAdd(&h[d.z >> 8], 1);
            atomicAdd(&h[d.w >> 8], 1);
        }
    } else {
        for (int i = base + tid; i < e && i < base + CHUNK; i += 256)
            atomicAdd(&h[dst[i] >> 8], 1);
    }
    __syncthreads();
    for (int k = tid; k < nbuck; k += 256)
        tableT[(size_t)k * nA + blk] = h[k];
}

__global__ __launch_bounds__(256) void k_bucket_scatter(const int* __restrict__ src,
                                                        const int* __restrict__ dst,
                                                        const int* __restrict__ tableT,
                                                        int2* __restrict__ bed,
                                                        int nA, int nbuck, int e) {
    __shared__ int cur[1024];
    int blk = blockIdx.x, tid = threadIdx.x;
    for (int k = tid; k < nbuck; k += 256)
        cur[k] = tableT[(size_t)k * nA + blk];
    __syncthreads();
    int base = blk * CHUNK;
    if (base + CHUNK <= e && (e & 3) == 0) {
        const int4* s4 = (const int4*)(src + base);
        const int4* d4 = (const int4*)(dst + base);
#pragma unroll
        for (int t = 0; t < 4; ++t) {
            int4 s = s4[t * 256 + tid];
            int4 d = d4[t * 256 + tid];
            int p0 = atomicAdd(&cur[d.x >> 8], 1); bed[p0] = make_int2(s.x, d.x);
            int p1 = atomicAdd(&cur[d.y >> 8], 1); bed[p1] = make_int2(s.y, d.y);
            int p2 = atomicAdd(&cur[d.z >> 8], 1); bed[p2] = make_int2(s.z, d.z);
            int p3 = atomicAdd(&cur[d.w >> 8], 1); bed[p3] = make_int2(s.w, d.w);
        }
    } else {
        for (int i = base + tid; i < e && i < base + CHUNK; i += 256) {
            int d = dst[i];
            int p = atomicAdd(&cur[d >> 8], 1);
            bed[p] = make_int2(src[i], d);
        }
    }
}

__global__ __launch_bounds__(256) void k_bucket_rank(const int2* __restrict__ bed,
                                                     const int* __restrict__ tableT,
                                                     int* __restrict__ brank,
                                                     int* __restrict__ counts,
                                                     int nA, int nbuck, int n, int e) {
    __shared__ int lcnt[256];
    int b = blockIdx.x, tid = threadIdx.x;
    lcnt[tid] = 0;
    __syncthreads();
    int start = tableT[(size_t)b * nA];
    int end = (b + 1 < nbuck) ? tableT[(size_t)(b + 1) * nA] : e;
    for (int i = start + tid; i < end; i += 256) {
        int2 q = bed[i];
        brank[i] = atomicAdd(&lcnt[q.y & 255], 1);
    }
    __syncthreads();
    int node = (b << 8) + tid;
    if (node < n) counts[node] = lcnt[tid];
}

__global__ __launch_bounds__(256) void k_dinv(const int* __restrict__ counts,
                                              float* __restrict__ dinv, int n) {
    int i = blockIdx.x * 256 + threadIdx.x;
    if (i < n) dinv[i] = rsqrtf((float)(counts[i] + 1));
}

template <bool PAD8>
__global__ __launch_bounds__(1024) void k_scan_block(const int* __restrict__ counts,
                                                     int* __restrict__ offs,
                                                     int* __restrict__ partials, int len) {
    __shared__ int s[1024];
    int t = threadIdx.x;
    int gid = blockIdx.x * 1024 + t;
    int c = (gid < len) ? counts[gid] : 0;
    int v = PAD8 ? ((c + 7) & ~7) : c;
    int x = v;
    s[t] = x;
    __syncthreads();
    for (int d = 1; d < 1024; d <<= 1) {
        int y = (t >= d) ? s[t - d] : 0;
        __syncthreads();
        x += y;
        s[t] = x;
        __syncthreads();
    }
    if (gid < len) offs[gid] = x - v;
    if (t == 1023) partials[blockIdx.x] = x;
}

__global__ __launch_bounds__(1024) void k_scan_partials(int* __restrict__ partials, int nb) {
    __shared__ int s[1024];
    int t = threadIdx.x;
    int v = (t < nb) ? partials[t] : 0;
    int x = v;
    s[t] = x;
    __syncthreads();
    for (int d = 1; d < 1024; d <<= 1) {
        int y = (t >= d) ? s[t - d] : 0;
        __syncthreads();
        x += y;
        s[t] = x;
        __syncthreads();
    }
    if (t < nb) partials[t] = x - v;
    if (t == nb - 1) partials[nb] = x;
}

__global__ __launch_bounds__(256) void k_scan_add(int* __restrict__ offs,
                                                  const int* __restrict__ partials, int len) {
    int gid = blockIdx.x * 256 + threadIdx.x;
    if (gid < len) offs[gid] += partials[gid >> 10];
    if (gid == 0) offs[len] = partials[(len + 1023) >> 10];
}

__global__ __launch_bounds__(256) void k_fill(int4* __restrict__ er4, int val, int m4) {
    int i = blockIdx.x * 256 + threadIdx.x;
    if (i < m4) er4[i] = make_int4(val, val, val, val);
}

__global__ __launch_bounds__(256) void k_place2(const int2* __restrict__ bed,
                                                const int* __restrict__ brank,
                                                const int* __restrict__ offs,
                                                int* __restrict__ er, int e) {
    int i = (blockIdx.x * 256 + threadIdx.x) * 2;
    if (i + 1 < e) {
        int4 q = *(const int4*)(bed + i);
        int2 r = *(const int2*)(brank + i);
        er[offs[q.y] + r.x] = q.x;
        er[offs[q.w] + r.y] = q.z;
    } else if (i < e) {
        int2 q = bed[i];
        er[offs[q.y] + brank[i]] = q.x;
    }
}

// ---------------- W pre-pack: f32 [128][128] -> f16 B-fragment order ----------------
// packed[((kc*8+ct)*64+lane)*8 + j] = W[kc*32 + (lane>>4)*8 + j][ct*16 + (lane&15)]
// so the GEMM's LDS read is a conflict-free lane-indexed ds_read_b128.

__global__ __launch_bounds__(256) void k_packW(const float* __restrict__ W,
                                               _Float16* __restrict__ out) {
    int t = blockIdx.x * 256 + threadIdx.x;     // 0..2047
    if (t >= 2048) return;
    int kc = t >> 9;
    int rem = t & 511;
    int ct = rem >> 6;
    int lane = rem & 63;
    int q = lane >> 4;
    int col = ct * 16 + (lane & 15);
    half8 h;
#pragma unroll
    for (int j = 0; j < 8; ++j)
        h[j] = (_Float16)W[(kc * 32 + q * 8 + j) * 128 + col];
    *(half8*)(out + (size_t)t * 8) = h;
}

// ---------------- MFMA GEMM: C[n,128](f16) = (A @ W) * dinv[row] ----------------
// 4 waves/block, wave = 16 rows x 128 cols = 8 tiles of 16x16, K=128 in 4 chunks of 32.
// A-frags straight from global (no staging); W from LDS (pre-packed frag order);
// epilogue transposes via LDS (reusing the W buffer) for coalesced f16 row writes.

template <bool AF32>
__global__ __launch_bounds__(256) void k_gemm_mfma(const void* __restrict__ Av,
                                                   const _Float16* __restrict__ pW,
                                                   const float* __restrict__ dinv,
                                                   uint4* __restrict__ C, int n) {
    __shared__ char smem[32768];
    uint4* sW = (uint4*)smem;
    int tid = threadIdx.x;

    {   // stage packed W: 2048 uint4, coalesced
        const uint4* gW = (const uint4*)pW;
#pragma unroll
        for (int i = 0; i < 8; ++i) sW[tid + 256 * i] = gW[tid + 256 * i];
    }
    __syncthreads();

    int wave = tid >> 6, lane = tid & 63;
    int quad = lane >> 4, l16 = lane & 15;
    int row0 = blockIdx.x * 64 + wave * 16;
    int arow = row0 + l16;
    int arowc = (arow < n) ? arow : (n - 1);

    // A-fragments: A[m=lane&15][k = quad*8 + j], k-chunks of 32
    half8 af[4];
    if (AF32) {
        const float* A = (const float*)Av + (size_t)arowc * 128 + quad * 8;
#pragma unroll
        for (int kc = 0; kc < 4; ++kc) {
            float4 lo = *(const float4*)(A + kc * 32);
            float4 hi = *(const float4*)(A + kc * 32 + 4);
            half8 h;
            h[0] = (_Float16)lo.x; h[1] = (_Float16)lo.y;
            h[2] = (_Float16)lo.z; h[3] = (_Float16)lo.w;
            h[4] = (_Float16)hi.x; h[5] = (_Float16)hi.y;
            h[6] = (_Float16)hi.z; h[7] = (_Float16)hi.w;
            af[kc] = h;
        }
    } else {
        const _Float16* A = (const _Float16*)Av + (size_t)arowc * 128 + quad * 8;
#pragma unroll
        for (int kc = 0; kc < 4; ++kc)
            af[kc] = *(const half8*)(A + kc * 32);
    }

    f32x4 acc[8];
#pragma unroll
    for (int ct = 0; ct < 8; ++ct) acc[ct] = (f32x4){0.f, 0.f, 0.f, 0.f};

#pragma unroll
    for (int kc = 0; kc < 4; ++kc) {
#pragma unroll
        for (int ct = 0; ct < 8; ++ct) {
            half8 bf = *(half8*)&sW[(kc * 8 + ct) * 64 + lane];
            acc[ct] = __builtin_amdgcn_mfma_f32_16x16x32_f16(af[kc], bf, acc[ct], 0, 0, 0);
        }
    }

    __syncthreads();   // everyone done reading sW; reuse as epilogue buffer

    // C/D layout: col = lane&15, row = quad*4 + reg  (dtype-independent, m89-verified)
    _Float16* eb = (_Float16*)smem + wave * 16 * 136;   // 136 = 128 + 8 pad
    float dv[4];
#pragma unroll
    for (int r = 0; r < 4; ++r) {
        int rr = row0 + quad * 4 + r;
        dv[r] = dinv[(rr < n) ? rr : (n - 1)];
    }
#pragma unroll
    for (int ct = 0; ct < 8; ++ct)
#pragma unroll
        for (int r = 0; r < 4; ++r)
            eb[(quad * 4 + r) * 136 + ct * 16 + l16] = (_Float16)(acc[ct][r] * dv[r]);

    // wave-local buffer; compiler inserts lgkmcnt waits before readback
#pragma unroll
    for (int i = 0; i < 4; ++i) {
        int linear = i * 64 + lane;
        int r = linear >> 4, c = linear & 15;
        uint4 v = *(uint4*)((char*)eb + r * 272 + c * 16);
        int row = row0 + r;
        if (row < n) C[(size_t)row * 16 + c] = v;
    }
}

// ---------------- CSR aggregation + bias + ReLU + BN (+ optional classifier) ----------------
// Writes H in f16 (GEMM reads f16 directly); out path (FUSE_CLS) unchanged f32.

__device__ __forceinline__ void acc_row(float4& acc, uint2 q) {
    float2 f01 = __half22float2(*(__half2*)&q.x);
    float2 f23 = __half22float2(*(__half2*)&q.y);
    acc.x += f01.x; acc.y += f01.y; acc.z += f23.x; acc.w += f23.y;
}

template <bool FUSE_CLS>
__global__ __launch_bounds__(256) void k_aggregate(const uint2* __restrict__ Ah,
                                                   const int* __restrict__ offs,
                                                   const int* __restrict__ er,
                                                   const float* __restrict__ dinv,
                                                   const float* __restrict__ bias,
                                                   const float* __restrict__ g,
                                                   const float* __restrict__ be,
                                                   const float* __restrict__ rm,
                                                   const float* __restrict__ rv,
                                                   uint2* __restrict__ Hout,
                                                   const float* __restrict__ Wc,
                                                   const float* __restrict__ bc,
                                                   float* __restrict__ out, int n) {
    int lane = threadIdx.x & 31;
    int node = blockIdx.x * 8 + (threadIdx.x >> 5);
    if (node >= n) return;

    float4 acc = f4zero();
    acc_row(acc, Ah[node * 32 + lane]);           // self loop

    int e0 = offs[node], e1 = offs[node + 1];
    for (int e = e0; e < e1; e += 8) {
        int4 ra = *(const int4*)(er + e);
        int4 rb = *(const int4*)(er + e + 4);
        uint2 v0 = Ah[ra.x * 32 + lane];
        uint2 v1 = Ah[ra.y * 32 + lane];
        uint2 v2 = Ah[ra.z * 32 + lane];
        uint2 v3 = Ah[ra.w * 32 + lane];
        uint2 v4 = Ah[rb.x * 32 + lane];
        uint2 v5 = Ah[rb.y * 32 + lane];
        uint2 v6 = Ah[rb.z * 32 + lane];
        uint2 v7 = Ah[rb.w * 32 + lane];
        acc_row(acc, v0); acc_row(acc, v1); acc_row(acc, v2); acc_row(acc, v3);
        acc_row(acc, v4); acc_row(acc, v5); acc_row(acc, v6); acc_row(acc, v7);
    }

    float di = dinv[node];
    acc.x *= di; acc.y *= di; acc.z *= di; acc.w *= di;

    float4 b4  = ((const float4*)bias)[lane];
    float4 g4  = ((const float4*)g)[lane];
    float4 be4 = ((const float4*)be)[lane];
    float4 rm4 = ((const float4*)rm)[lane];
    float4 rv4 = ((const float4*)rv)[lane];

    float4 o;
    float v;
    v = fmaxf(acc.x + b4.x, 0.f); o.x = (v - rm4.x) * rsqrtf(rv4.x + BN_EPS) * g4.x + be4.x;
    v = fmaxf(acc.y + b4.y, 0.f); o.y = (v - rm4.y) * rsqrtf(rv4.y + BN_EPS) * g4.y + be4.y;
    v = fmaxf(acc.z + b4.z, 0.f); o.z = (v - rm4.z) * rsqrtf(rv4.z + BN_EPS) * g4.z + be4.z;
    v = fmaxf(acc.w + b4.w, 0.f); o.w = (v - rm4.w) * rsqrtf(rv4.w + BN_EPS) * g4.w + be4.w;

    if (!FUSE_CLS) {
        __half2 p0 = __floats2half2_rn(o.x, o.y);
        __half2 p1 = __floats2half2_rn(o.z, o.w);
        uint2 u;
        u.x = *(unsigned int*)&p0;
        u.y = *(unsigned int*)&p1;
        Hout[node * 32 + lane] = u;
    } else {
        const float4* Wv = (const float4*)Wc;
        float4 w01 = Wv[2 * lane];
        float4 w23 = Wv[2 * lane + 1];
        float p0 = o.x * w01.x + o.y * w01.z + o.z * w23.x + o.w * w23.z;
        float p1 = o.x * w01.y + o.y * w01.w + o.z * w23.y + o.w * w23.w;
#pragma unroll
        for (int d = 16; d >= 1; d >>= 1) {
            p0 += __shfl_down(p0, d, 32);
            p1 += __shfl_down(p1, d, 32);
        }
        if (lane == 0) {
            out[node * 2 + 0] = p0 + bc[0];
            out[node * 2 + 1] = p1 + bc[1];
        }
    }
}

// ---------------- launch ----------------

extern "C" void kernel_launch(void* const* d_in, const int* in_sizes, int n_in,
                              void* d_out, int out_size, void* d_ws, size_t ws_size,
                              hipStream_t stream) {
    const float* x   = (const float*)d_in[0];
    const int*   ei  = (const int*)d_in[1];
    const float* W1  = (const float*)d_in[2];
    const float* b1  = (const float*)d_in[3];
    const float* W2  = (const float*)d_in[4];
    const float* b2  = (const float*)d_in[5];
    const float* W3  = (const float*)d_in[6];
    const float* b3  = (const float*)d_in[7];
    const float* g1  = (const float*)d_in[8];
    const float* be1 = (const float*)d_in[9];
    const float* rm1 = (const float*)d_in[10];
    const float* rv1 = (const float*)d_in[11];
    const float* g2  = (const float*)d_in[12];
    const float* be2 = (const float*)d_in[13];
    const float* rm2 = (const float*)d_in[14];
    const float* rv2 = (const float*)d_in[15];
    const float* g3  = (const float*)d_in[16];
    const float* be3 = (const float*)d_in[17];
    const float* rm3 = (const float*)d_in[18];
    const float* rv3 = (const float*)d_in[19];
    const float* Wc  = (const float*)d_in[20];
    const float* bc  = (const float*)d_in[21];
    float* out = (float*)d_out;

    int n = in_sizes[0] / 128;
    int e = in_sizes[1] / 2;
    const int* src = ei;
    const int* dst = ei + e;

    char* ws = (char*)d_ws;
    size_t off = 0;
    auto alloc = [&](size_t bytes) -> char* {
        char* p = ws + off;
        off += (bytes + 255) & ~(size_t)255;
        return p;
    };
    int erCap = e + 8 * n;
    uint2*     bufA   = (uint2*)alloc((size_t)(n + 1) * 128 * 2); // GEMM out f16, +1 zero row
    char*      bufH   = (char*) alloc((size_t)n * 128 * 4);       // H f16 (n*128*2) + prep scratch alias
    float*     dinv   = (float*)alloc((size_t)n * 4);
    int*       counts = (int*)  alloc((size_t)n * 4);
    int*       offs   = (int*)  alloc((size_t)(n + 1) * 4);
    int*       parts  = (int*)  alloc(8192);
    int*       er     = (int*)  alloc((size_t)erCap * 4);
    _Float16*  pW     = (_Float16*)alloc(3 * 16384 * 2);          // packed W frags
    (void)ws_size; (void)n_in; (void)out_size;

    int nA    = (e + CHUNK - 1) / CHUNK;
    int nbuck = (n + 255) >> 8;
    int tlen  = nbuck * nA;
    {
        // prep scratch aliased past the H region of bufH (H uses n*128*2 bytes)
        char* p = bufH + (size_t)n * 128 * 2;
        size_t po = 0;
        auto palloc = [&](size_t bytes) -> char* {
            char* q = p + po;
            po += (bytes + 255) & ~(size_t)255;
            return q;
        };
        // scratch need: e*8 + e*4 + tlen*4 ~= 19.9 MB < n*128*2 = 25.6 MB available
        int2* bed    = (int2*)palloc((size_t)e * 8);
        int*  brank  = (int*) palloc((size_t)e * 4);
        int*  tableT = (int*) palloc((size_t)(tlen + 1) * 4);

        hipMemsetAsync(bufA + (size_t)n * 32, 0, 256, stream);  // zero row n (padding target)

        int gN  = (n + 255) / 256;
        int nb  = (n + 1023) / 1024;
        int nbT = (tlen + 1023) / 1024;
        int m4  = erCap / 4;

        k_packW<<<8, 256, 0, stream>>>(W1, pW);
        k_packW<<<8, 256, 0, stream>>>(W2, pW + 16384);
        k_packW<<<8, 256, 0, stream>>>(W3, pW + 32768);
        k_bucket_hist<<<nA, 256, 0, stream>>>(dst, tableT, nA, nbuck, e);
        k_scan_block<false><<<nbT, 1024, 0, stream>>>(tableT, tableT, parts, tlen);
        k_scan_partials<<<1, 1024, 0, stream>>>(parts, nbT);
        k_scan_add<<<(tlen + 255) / 256, 256, 0, stream>>>(tableT, parts, tlen);
        k_bucket_scatter<<<nA, 256, 0, stream>>>(src, dst, tableT, bed, nA, nbuck, e);
        k_bucket_rank<<<nbuck, 256, 0, stream>>>(bed, tableT, brank, counts, nA, nbuck, n, e);
        k_dinv<<<gN, 256, 0, stream>>>(counts, dinv, n);
        k_scan_block<true><<<nb, 1024, 0, stream>>>(counts, offs, parts, n);
        k_scan_partials<<<1, 1024, 0, stream>>>(parts, nb);
        k_scan_add<<<gN, 256, 0, stream>>>(offs, parts, n);
        k_fill<<<(m4 + 255) / 256, 256, 0, stream>>>((int4*)er, n, m4);
        k_place2<<<((e + 1) / 2 + 255) / 256, 256, 0, stream>>>(bed, brank, offs, er, e);
    }

    int gGemm = (n + 63) / 64;
    int gAgg  = (n + 7) / 8;

    k_gemm_mfma<true><<<gGemm, 256, 0, stream>>>(x, pW, dinv, (uint4*)bufA, n);
    k_aggregate<false><<<gAgg, 256, 0, stream>>>(bufA, offs, er, dinv,
                                                 b1, g1, be1, rm1, rv1, (uint2*)bufH,
                                                 nullptr, nullptr, nullptr, n);

    k_gemm_mfma<false><<<gGemm, 256, 0, stream>>>(bufH, pW + 16384, dinv, (uint4*)bufA, n);
    k_aggregate<false><<<gAgg, 256, 0, stream>>>(bufA, offs, er, dinv,
                                                 b2, g2, be2, rm2, rv2, (uint2*)bufH,
                                                 nullptr, nullptr, nullptr, n);

    k_gemm_mfma<false><<<gGemm, 256, 0, stream>>>(bufH, pW + 32768, dinv, (uint4*)bufA, n);
    k_aggregate<true><<<gAgg, 256, 0, stream>>>(bufA, offs, er, dinv,
                                                b3, g3, be3, rm3, rv3, nullptr,
                                                Wc, bc, out, n);
}